// Round 8
// baseline (8962.712 us; speedup 1.0000x reference)
//
#include <hip/hip_runtime.h>
#include <math.h>

#define HDIM 512
#define TPB  512
#define NT   1                // neurons per thread (1*512 = 512)
#define NWAVES (TPB/64)       // 8 waves per block
#define MI   (HDIM/16/NWAVES) // M-tiles per wave = 4
#define SSTR 516              // LDS f32 row stride (512 + 4 pad)
#define NCH  22               // 1 value + 8 grads + 13 hessian pairs
#define NPR  13
#define NRED 57
#define LN_EPS 1e-5f

typedef _Float16 f16x8 __attribute__((ext_vector_type(8)));
typedef float    f32x4 __attribute__((ext_vector_type(4)));

// Needed Hessian pairs (a<=b, b>=4): 26 total, split 13/13 across passes.
template<int P> struct PairSet;
template<> struct PairSet<0> {
    static constexpr int A[NPR] = {0,1,2,3,4, 0,1,2,3,4,5, 0,1};
    static constexpr int B[NPR] = {4,4,4,4,4, 5,5,5,5,5,5, 6,6};
};
template<> struct PairSet<1> {
    static constexpr int A[NPR] = {2,3,4,5,6, 0,1,2,3,4,5,6,7};
    static constexpr int B[NPR] = {6,6,6,6,6, 7,7,7,7,7,7,7,7};
};

// ---------- DPP wave-64 sum (VALU pipe, not DS). Result valid in lane 63. ----------
template<int CTRL>
__device__ __forceinline__ float dpp_add(float x) {
    int v = __builtin_amdgcn_update_dpp(0, __builtin_bit_cast(int, x),
                                        CTRL, 0xf, 0xf, true);
    return x + __builtin_bit_cast(float, v);
}
__device__ __forceinline__ float wave_sum_dpp(float x) {
    x = dpp_add<0x111>(x);   // row_shr:1
    x = dpp_add<0x112>(x);   // row_shr:2
    x = dpp_add<0x114>(x);   // row_shr:4
    x = dpp_add<0x118>(x);   // row_shr:8
    x = dpp_add<0x142>(x);   // row_bcast:15
    x = dpp_add<0x143>(x);   // row_bcast:31 -> lane63 = full wave sum
    return x;
}

// ---------- prep: W1,W2 f32 -> hi/lo f16 in MFMA-fragment-contiguous layout ----------
// element (i,j) -> off = (((mt*16+ks)*4+q)*16+m)*8+e
// lo scaled by 1024 to stay in f16 normal range.
__global__ void prep_kernel(const float* __restrict__ W1, const float* __restrict__ W2,
                            _Float16* __restrict__ ws) {
    const int gid  = blockIdx.x * 256 + threadIdx.x;
    const int layer = gid >> 18;
    const int r     = gid & 262143;
    const int i = r >> 9, j = r & 511;
    const float v = (layer ? W2 : W1)[r];
    const _Float16 hi = (_Float16)v;
    const _Float16 lo = (_Float16)((v - (float)hi) * 1024.f);
    const int mt = i >> 4, m = i & 15, ks = j >> 5, q = (j >> 3) & 3, e = j & 7;
    const int off = (((mt * 16 + ks) * 4 + q) * 16 + m) * 8 + e;
    _Float16* base = ws + (size_t)layer * 524288;
    base[off] = hi;
    base[262144 + off] = lo;
}

// ---------- MFMA gemm: D[512, 22] = W * S, result staged back into S (ch-major) ----------
// A = W (M=neuron, K=j) from global fragment layout; B = S (K=j, N=ch) from LDS.
// D = Whi*Shi + (1/1024)*(Whi*Slo + Wlo*Shi), lo = 1024*(x - hi). One accumulator,
// two k-sweeps with a rescale in between (avoids 2x acc registers).
__device__ void gemm_mfma(float* __restrict__ S,
                          const _Float16* __restrict__ Whi,
                          const _Float16* __restrict__ Wlo,
                          int w, int lane)
{
    const int q = lane >> 4, m = lane & 15;
    const int ch0 = m;
    const int ch1 = (16 + m < NCH) ? (16 + m) : (NCH - 1);  // clamp garbage lanes
    f32x4 acc[MI][2];
    #pragma unroll
    for (int mi = 0; mi < MI; ++mi) {
        acc[mi][0] = (f32x4){0.f, 0.f, 0.f, 0.f};
        acc[mi][1] = (f32x4){0.f, 0.f, 0.f, 0.f};
    }

    // ---- sweep A: cross terms Whi*Slo + Wlo*Shi ----
    #pragma unroll 1
    for (int ks = 0; ks < 16; ++ks) {
        f16x8 Bhi[2], Blo[2];
        #pragma unroll
        for (int nt = 0; nt < 2; ++nt) {
            const int ch = nt ? ch1 : ch0;
            const float* sp = S + ch * SSTR + ks * 32 + q * 8;
            const float4 v0 = *(const float4*)sp;
            const float4 v1 = *(const float4*)(sp + 4);
            const float vv[8] = {v0.x, v0.y, v0.z, v0.w, v1.x, v1.y, v1.z, v1.w};
            #pragma unroll
            for (int e = 0; e < 8; ++e) {
                const _Float16 h = (_Float16)vv[e];
                Bhi[nt][e] = h;
                Blo[nt][e] = (_Float16)((vv[e] - (float)h) * 1024.f);
            }
        }
        #pragma unroll
        for (int mi = 0; mi < MI; ++mi) {
            const size_t fo = ((size_t)((w * MI + mi) * 16 + ks) * 64 + lane) * 8;
            const f16x8 Ahi = *(const f16x8*)(Whi + fo);
            const f16x8 Alo = *(const f16x8*)(Wlo + fo);
            acc[mi][0] = __builtin_amdgcn_mfma_f32_16x16x32_f16(Ahi, Blo[0], acc[mi][0], 0, 0, 0);
            acc[mi][0] = __builtin_amdgcn_mfma_f32_16x16x32_f16(Alo, Bhi[0], acc[mi][0], 0, 0, 0);
            acc[mi][1] = __builtin_amdgcn_mfma_f32_16x16x32_f16(Ahi, Blo[1], acc[mi][1], 0, 0, 0);
            acc[mi][1] = __builtin_amdgcn_mfma_f32_16x16x32_f16(Alo, Bhi[1], acc[mi][1], 0, 0, 0);
        }
    }
    #pragma unroll
    for (int mi = 0; mi < MI; ++mi) {
        acc[mi][0] *= (1.f / 1024.f);
        acc[mi][1] *= (1.f / 1024.f);
    }
    // ---- sweep B: main term Whi*Shi ----
    #pragma unroll 1
    for (int ks = 0; ks < 16; ++ks) {
        f16x8 Bhi[2];
        #pragma unroll
        for (int nt = 0; nt < 2; ++nt) {
            const int ch = nt ? ch1 : ch0;
            const float* sp = S + ch * SSTR + ks * 32 + q * 8;
            const float4 v0 = *(const float4*)sp;
            const float4 v1 = *(const float4*)(sp + 4);
            const float vv[8] = {v0.x, v0.y, v0.z, v0.w, v1.x, v1.y, v1.z, v1.w};
            #pragma unroll
            for (int e = 0; e < 8; ++e) Bhi[nt][e] = (_Float16)vv[e];
        }
        #pragma unroll
        for (int mi = 0; mi < MI; ++mi) {
            const size_t fo = ((size_t)((w * MI + mi) * 16 + ks) * 64 + lane) * 8;
            const f16x8 Ahi = *(const f16x8*)(Whi + fo);
            acc[mi][0] = __builtin_amdgcn_mfma_f32_16x16x32_f16(Ahi, Bhi[0], acc[mi][0], 0, 0, 0);
            acc[mi][1] = __builtin_amdgcn_mfma_f32_16x16x32_f16(Ahi, Bhi[1], acc[mi][1], 0, 0, 0);
        }
    }

    __syncthreads();   // all waves done reading S -> safe to overwrite with D
    #pragma unroll
    for (int mi = 0; mi < MI; ++mi) {
        #pragma unroll
        for (int nt = 0; nt < 2; ++nt) {
            const int ch = nt * 16 + m;
            if (ch < NCH) {
                const float4 st = {acc[mi][nt][0], acc[mi][nt][1], acc[mi][nt][2], acc[mi][nt][3]};
                *(float4*)(S + ch * SSTR + (w * MI + mi) * 16 + q * 4) = st;
            }
        }
    }
    __syncthreads();
}

__device__ __forceinline__ void readback(float (&vals)[NT][NCH],
                                         const float* __restrict__ b,
                                         const float* __restrict__ S, int tid)
{
    #pragma unroll
    for (int m = 0; m < NT; ++m) {
        const int j = NT * tid + m;
        #pragma unroll
        for (int ch = 0; ch < NCH; ++ch) vals[m][ch] = S[ch * SSTR + j];
        vals[m][0] += b[j];
    }
}

// ---------- softplus chain + LN; writes S (ch-major) or accumulates final linear ----------
template<int P, bool FINAL>
__device__ void ln_process(float (&vals)[NT][NCH],
        const float* __restrict__ g, const float* __restrict__ be,
        float* __restrict__ S, float* __restrict__ red, float* __restrict__ fin,
        float* __restrict__ sJ, float* __restrict__ sH,
        int tid, int lane, int w, float w3x)
{
    float p[NRED];
    #pragma unroll
    for (int k = 0; k < NRED; ++k) p[k] = 0.f;

    #pragma unroll
    for (int m = 0; m < NT; ++m) {
        const float pv  = vals[m][0];
        const float e   = expf(-fabsf(pv));
        const float sig = (pv >= 0.f) ? (1.f / (1.f + e)) : (e / (1.f + e));
        const float h   = fmaxf(pv, 0.f) + log1pf(e);
        const float spp = sig * (1.f - sig);
        #pragma unroll
        for (int t = 0; t < NPR; ++t) {
            const int a = PairSet<P>::A[t], b = PairSet<P>::B[t];
            vals[m][9+t] = sig * vals[m][9+t] + spp * vals[m][1+a] * vals[m][1+b];
        }
        #pragma unroll
        for (int a = 0; a < 8; ++a) vals[m][1+a] *= sig;
        vals[m][0] = h;

        p[0] += h;
        p[1] += h * h;
        #pragma unroll
        for (int a = 0; a < 8; ++a) { p[2+a] += vals[m][1+a]; p[10+a] += h * vals[m][1+a]; }
        #pragma unroll
        for (int t = 0; t < NPR; ++t) {
            const int a = PairSet<P>::A[t], b = PairSet<P>::B[t];
            p[18+t] += vals[m][9+t];
            p[31+t] += vals[m][1+a] * vals[m][1+b];
            p[44+t] += h * vals[m][9+t];
        }
    }

    #pragma unroll
    for (int k = 0; k < NRED; ++k) p[k] = wave_sum_dpp(p[k]);
    if (lane == 63) {
        #pragma unroll
        for (int k = 0; k < NRED; ++k) red[w * NRED + k] = p[k];
    }
    __syncthreads();
    if (tid < NRED) {
        float s = 0.f;
        #pragma unroll
        for (int k = 0; k < NWAVES; ++k) s += red[k * NRED + tid];
        fin[tid] = s;
    }
    __syncthreads();

    const float invH = 1.f / HDIM;
    const float mean = fin[0] * invH;
    const float var  = fin[1] * invH - mean * mean;
    const float rs   = rsqrtf(var + LN_EPS);
    float mdot[8], sdot[8];
    #pragma unroll
    for (int a = 0; a < 8; ++a) {
        mdot[a] = fin[2+a] * invH;
        sdot[a] = (fin[10+a] * invH - mean * mdot[a]) * rs;
    }
    float mdd[NPR], cy[NPR];
    #pragma unroll
    for (int t = 0; t < NPR; ++t) {
        const int a = PairSet<P>::A[t], b = PairSet<P>::B[t];
        mdd[t] = fin[18+t] * invH;
        const float mcc = fin[31+t] * invH - mdot[a] * mdot[b];
        const float mch = fin[44+t] * invH - mean * mdd[t];
        const float vdd = 2.f * (mcc + mch);
        const float sdd = (0.5f * vdd - sdot[a] * sdot[b]) * rs;
        cy[t] = 2.f * sdot[a] * sdot[b] * rs * rs - sdd * rs;
    }

    if (!FINAL) {
        #pragma unroll
        for (int m = 0; m < NT; ++m) {
            const int j = NT * tid + m;
            const float gi = g[j], bi = be[j];
            const float y = (vals[m][0] - mean) * rs;
            S[0 * SSTR + j] = y * gi + bi;
            float cd[8];
            #pragma unroll
            for (int a = 0; a < 8; ++a) {
                cd[a] = vals[m][1+a] - mdot[a];
                S[(1+a) * SSTR + j] = (cd[a] - y * sdot[a]) * rs * gi;
            }
            #pragma unroll
            for (int t = 0; t < NPR; ++t) {
                const int a = PairSet<P>::A[t], b = PairSet<P>::B[t];
                const float cdd = vals[m][9+t] - mdd[t];
                const float ydd = cdd * rs - (cd[a]*sdot[b] + cd[b]*sdot[a]) * rs * rs
                                  + y * cy[t];
                S[(9+t) * SSTR + j] = ydd * gi;
            }
        }
    } else {
        float pf[NCH];
        #pragma unroll
        for (int k = 0; k < NCH; ++k) pf[k] = 0.f;
        #pragma unroll
        for (int m = 0; m < NT; ++m) {
            const int j = NT * tid + m;
            const float gi = g[j], bi = be[j];
            const float w3 = w3x;
            const float y = (vals[m][0] - mean) * rs;
            pf[0] += w3 * (y * gi + bi);
            float cd[8];
            #pragma unroll
            for (int a = 0; a < 8; ++a) {
                cd[a] = vals[m][1+a] - mdot[a];
                pf[1+a] += w3 * ((cd[a] - y * sdot[a]) * rs * gi);
            }
            #pragma unroll
            for (int t = 0; t < NPR; ++t) {
                const int a = PairSet<P>::A[t], b = PairSet<P>::B[t];
                const float cdd = vals[m][9+t] - mdd[t];
                const float ydd = cdd * rs - (cd[a]*sdot[b] + cd[b]*sdot[a]) * rs * rs
                                  + y * cy[t];
                pf[9+t] += w3 * (ydd * gi);
            }
        }
        #pragma unroll
        for (int k = 0; k < NCH; ++k) pf[k] = wave_sum_dpp(pf[k]);
        if (lane == 63) {
            #pragma unroll
            for (int k = 0; k < NCH; ++k) red[w * NRED + k] = pf[k];
        }
        __syncthreads();
        if (tid < NCH) {
            float s = 0.f;
            #pragma unroll
            for (int k = 0; k < NWAVES; ++k) s += red[k * NRED + tid];
            fin[tid] = s;
        }
        __syncthreads();
        if (tid == 0) {
            if (P == 0) {
                #pragma unroll
                for (int a = 0; a < 8; ++a) sJ[a] = fin[1 + a];
            }
            #pragma unroll
            for (int t = 0; t < NPR; ++t) sH[P * NPR + t] = fin[9 + t];
        }
    }
}

template<int P>
__device__ void run_pass(int tid, int lane, int w, const float (&q)[8],
        const float* __restrict__ W0, const float* __restrict__ b0,
        const float* __restrict__ g0, const float* __restrict__ be0,
        const float* __restrict__ b1, const float* __restrict__ g1,
        const float* __restrict__ be1,
        const float* __restrict__ b2, const float* __restrict__ g2,
        const float* __restrict__ be2,
        const _Float16* __restrict__ Wf,
        float w3x,
        float* S, float* red, float* fin, float* sJ, float* sH)
{
    float vals[NT][NCH];

    // ---- layer 0: q(8) -> 512 (no gemm); grads = W0 row, hess = 0
    #pragma unroll
    for (int m = 0; m < NT; ++m) {
        const int i = NT * tid + m;
        const float4 wa = *(const float4*)(W0 + i * 8);
        const float4 wb = *(const float4*)(W0 + i * 8 + 4);
        vals[m][0] = b0[i]
            + wa.x*q[0] + wa.y*q[1] + wa.z*q[2] + wa.w*q[3]
            + wb.x*q[4] + wb.y*q[5] + wb.z*q[6] + wb.w*q[7];
        vals[m][1] = wa.x; vals[m][2] = wa.y; vals[m][3] = wa.z; vals[m][4] = wa.w;
        vals[m][5] = wb.x; vals[m][6] = wb.y; vals[m][7] = wb.z; vals[m][8] = wb.w;
        #pragma unroll
        for (int t = 0; t < NPR; ++t) vals[m][9+t] = 0.f;
    }
    ln_process<P, false>(vals, g0, be0, S, red, fin, sJ, sH, tid, lane, w, w3x);
    __syncthreads();

    // ---- layer 1
    gemm_mfma(S, Wf, Wf + 262144, w, lane);
    readback(vals, b1, S, tid);
    ln_process<P, false>(vals, g1, be1, S, red, fin, sJ, sH, tid, lane, w, w3x);
    __syncthreads();

    // ---- layer 2
    gemm_mfma(S, Wf + 524288, Wf + 786432, w, lane);
    readback(vals, b2, S, tid);
    ln_process<P, true>(vals, g2, be2, S, red, fin, sJ, sH, tid, lane, w, w3x);
    __syncthreads();
}

__global__ __launch_bounds__(TPB, 6)
void lnn_kernel(const float* __restrict__ x,
    const float* __restrict__ W0, const float* __restrict__ b0,
    const float* __restrict__ g0, const float* __restrict__ be0,
    const float* __restrict__ b1, const float* __restrict__ g1,
    const float* __restrict__ be1,
    const float* __restrict__ b2, const float* __restrict__ g2,
    const float* __restrict__ be2,
    const float* __restrict__ W3,
    const _Float16* __restrict__ Wf,
    float* __restrict__ out)
{
    __shared__ __align__(16) float S[NCH * SSTR];   // 45.4 KB: state / D-staging
    __shared__ __align__(16) float red[NWAVES * NRED];
    __shared__ __align__(16) float fin[NRED + 3];
    __shared__ float sJ[8];
    __shared__ float sH[26];

    const int tid  = threadIdx.x;
    const int lane = tid & 63;
    const int w    = tid >> 6;
    const long sample = blockIdx.x;

    float q[8];
    #pragma unroll
    for (int a = 0; a < 8; ++a) q[a] = x[sample * 8 + a];
    const float w3x = W3[tid];

    run_pass<0>(tid, lane, w, q, W0, b0, g0, be0, b1, g1, be1, b2, g2, be2,
                Wf, w3x, S, red, fin, sJ, sH);
    run_pass<1>(tid, lane, w, q, W0, b0, g0, be0, b1, g1, be1, b2, g2, be2,
                Wf, w3x, S, red, fin, sJ, sH);

    if (tid == 0) {
        const int off[4] = {0, 5, 11, 18};
        double Hd[26];
        for (int t = 0; t < 26; ++t) Hd[t] = (double)sH[t];
        double r[4];
        for (int k = 0; k < 4; ++k) {
            double s = (double)sJ[k];
            for (int j = 0; j < 4; ++j) s -= Hd[off[k] + j] * (double)q[4 + j];
            r[k] = s;
        }
        double A[4][5];
        for (int jj = 0; jj < 4; ++jj) {
            for (int k = 0; k < 4; ++k) {
                const int lo = (jj < k ? jj : k) + 4;
                const int hi = (jj < k ? k : jj) + 4;
                A[jj][k] = Hd[off[hi - 4] + lo];
            }
            A[jj][4] = r[jj];
        }
        for (int c = 0; c < 4; ++c) {
            int pr = c; double mx = fabs(A[c][c]);
            for (int rr = c + 1; rr < 4; ++rr)
                if (fabs(A[rr][c]) > mx) { mx = fabs(A[rr][c]); pr = rr; }
            if (pr != c)
                for (int cc = c; cc < 5; ++cc) {
                    double t = A[c][cc]; A[c][cc] = A[pr][cc]; A[pr][cc] = t;
                }
            const double pinv = 1.0 / A[c][c];
            for (int rr = 0; rr < 4; ++rr) if (rr != c) {
                const double f = A[rr][c] * pinv;
                for (int cc = c; cc < 5; ++cc) A[rr][cc] -= f * A[c][cc];
            }
        }
        #pragma unroll
        for (int k = 0; k < 4; ++k)
            out[sample * 4 + k] = (float)(A[k][4] / A[k][k]);
    }
}

extern "C" void kernel_launch(void* const* d_in, const int* in_sizes, int n_in,
                              void* d_out, int out_size, void* d_ws, size_t ws_size,
                              hipStream_t stream) {
    const float* x   = (const float*)d_in[0];
    const float* W0  = (const float*)d_in[1];
    const float* b0  = (const float*)d_in[2];
    const float* g0  = (const float*)d_in[3];
    const float* be0 = (const float*)d_in[4];
    const float* W1  = (const float*)d_in[5];
    const float* b1  = (const float*)d_in[6];
    const float* g1  = (const float*)d_in[7];
    const float* be1 = (const float*)d_in[8];
    const float* W2  = (const float*)d_in[9];
    const float* b2  = (const float*)d_in[10];
    const float* g2  = (const float*)d_in[11];
    const float* be2 = (const float*)d_in[12];
    const float* W3  = (const float*)d_in[13];
    float* out = (float*)d_out;

    _Float16* Wf = (_Float16*)d_ws;   // 2 MB: [W1hi|W1lo|W2hi|W2lo] fragment layout
    const int B = in_sizes[0] / 8;    // 16384

    hipLaunchKernelGGL(prep_kernel, dim3(2048), dim3(256), 0, stream, W1, W2, Wf);
    hipLaunchKernelGGL(lnn_kernel, dim3(B), dim3(TPB), 0, stream,
                       x, W0, b0, g0, be0, b1, g1, be1, b2, g2, be2, W3, Wf, out);
}

// Round 9
// 5953.083 us; speedup vs baseline: 1.5056x; 1.5056x over previous
//
#include <hip/hip_runtime.h>
#include <math.h>

#define HDIM 512
#define TPB  256
#define SSTR 516              // LDS f32 row stride (512 + 4 pad)
#define NCH  22               // 1 value + 8 grads + 13 hessian pairs
#define NPR  13
#define NRED 57
#define LN_EPS 1e-5f

typedef _Float16 f16x8 __attribute__((ext_vector_type(8)));
typedef _Float16 f16x2 __attribute__((ext_vector_type(2)));
typedef float    f32x4 __attribute__((ext_vector_type(4)));

// Needed Hessian pairs (a<=b, b>=4): 26 total, split 13/13 across passes.
template<int P> struct PairSet;
template<> struct PairSet<0> {
    static constexpr int A[NPR] = {0,1,2,3,4, 0,1,2,3,4,5, 0,1};
    static constexpr int B[NPR] = {4,4,4,4,4, 5,5,5,5,5,5, 6,6};
};
template<> struct PairSet<1> {
    static constexpr int A[NPR] = {2,3,4,5,6, 0,1,2,3,4,5,6,7};
    static constexpr int B[NPR] = {6,6,6,6,6, 7,7,7,7,7,7,7,7};
};

// ---------- DPP wave-64 sum (VALU pipe, not DS). Result valid in lane 63. ----------
template<int CTRL>
__device__ __forceinline__ float dpp_add(float x) {
    int v = __builtin_amdgcn_update_dpp(0, __builtin_bit_cast(int, x),
                                        CTRL, 0xf, 0xf, true);
    return x + __builtin_bit_cast(float, v);
}
__device__ __forceinline__ float wave_sum_dpp(float x) {
    x = dpp_add<0x111>(x);   // row_shr:1
    x = dpp_add<0x112>(x);   // row_shr:2
    x = dpp_add<0x114>(x);   // row_shr:4
    x = dpp_add<0x118>(x);   // row_shr:8
    x = dpp_add<0x142>(x);   // row_bcast:15
    x = dpp_add<0x143>(x);   // row_bcast:31 -> lane63 = full wave sum
    return x;
}

// ---------- packed f32->f16 conversion helpers (v_cvt_pkrtz_f16_f32) ----------
// rtz rounding; hi is rtz-consistent across both sweeps (same helper, same input).
__device__ __forceinline__ f16x8 pack_hi8(const float4 v0, const float4 v1) {
    union { f16x2 h[4]; f16x8 v8; } u;
    u.h[0] = __builtin_bit_cast(f16x2, __builtin_amdgcn_cvt_pkrtz(v0.x, v0.y));
    u.h[1] = __builtin_bit_cast(f16x2, __builtin_amdgcn_cvt_pkrtz(v0.z, v0.w));
    u.h[2] = __builtin_bit_cast(f16x2, __builtin_amdgcn_cvt_pkrtz(v1.x, v1.y));
    u.h[3] = __builtin_bit_cast(f16x2, __builtin_amdgcn_cvt_pkrtz(v1.z, v1.w));
    return u.v8;
}
__device__ __forceinline__ f16x8 pack_lo8(const float4 v0, const float4 v1, const f16x8 hi) {
    union { f16x2 h[4]; f16x8 v8; } u;
    u.h[0] = __builtin_bit_cast(f16x2, __builtin_amdgcn_cvt_pkrtz(
        (v0.x - (float)hi[0]) * 1024.f, (v0.y - (float)hi[1]) * 1024.f));
    u.h[1] = __builtin_bit_cast(f16x2, __builtin_amdgcn_cvt_pkrtz(
        (v0.z - (float)hi[2]) * 1024.f, (v0.w - (float)hi[3]) * 1024.f));
    u.h[2] = __builtin_bit_cast(f16x2, __builtin_amdgcn_cvt_pkrtz(
        (v1.x - (float)hi[4]) * 1024.f, (v1.y - (float)hi[5]) * 1024.f));
    u.h[3] = __builtin_bit_cast(f16x2, __builtin_amdgcn_cvt_pkrtz(
        (v1.z - (float)hi[6]) * 1024.f, (v1.w - (float)hi[7]) * 1024.f));
    return u.v8;
}

// ---------- prep: W1,W2 f32 -> hi/lo f16 in MFMA-fragment-contiguous layout ----------
// element (i,j) -> off = (((mt*16+ks)*4+q)*16+m)*8+e
// lo scaled by 1024 to stay in f16 normal range.
__global__ void prep_kernel(const float* __restrict__ W1, const float* __restrict__ W2,
                            _Float16* __restrict__ ws) {
    const int gid  = blockIdx.x * 256 + threadIdx.x;
    const int layer = gid >> 18;
    const int r     = gid & 262143;
    const int i = r >> 9, j = r & 511;
    const float v = (layer ? W2 : W1)[r];
    const _Float16 hi = (_Float16)v;
    const _Float16 lo = (_Float16)((v - (float)hi) * 1024.f);
    const int mt = i >> 4, m = i & 15, ks = j >> 5, q = (j >> 3) & 3, e = j & 7;
    const int off = (((mt * 16 + ks) * 4 + q) * 16 + m) * 8 + e;
    _Float16* base = ws + (size_t)layer * 524288;
    base[off] = hi;
    base[262144 + off] = lo;
}

// ---------- MFMA gemm: D[512, 22] = W * S, result staged back into S (ch-major) ----------
// A = W (M=neuron, K=j) from global fragment layout; B = S (K=j, N=ch) from LDS.
// D = Whi*Shi + (1/1024)*(Whi*Slo + Wlo*Shi), lo = 1024*(x - hi). One accumulator,
// two k-sweeps with a rescale in between (avoids 2x acc registers).
__device__ void gemm_mfma(float* __restrict__ S,
                          const _Float16* __restrict__ Whi,
                          const _Float16* __restrict__ Wlo,
                          int w, int lane)
{
    const int q = lane >> 4, m = lane & 15;
    const int ch0 = m;
    const int ch1 = (16 + m < NCH) ? (16 + m) : (NCH - 1);  // clamp garbage lanes
    f32x4 acc[8][2];
    #pragma unroll
    for (int mi = 0; mi < 8; ++mi) {
        acc[mi][0] = (f32x4){0.f, 0.f, 0.f, 0.f};
        acc[mi][1] = (f32x4){0.f, 0.f, 0.f, 0.f};
    }

    // ---- sweep A: cross terms Whi*Slo + Wlo*Shi ----
    #pragma unroll 1
    for (int ks = 0; ks < 16; ++ks) {
        f16x8 Bhi[2], Blo[2];
        #pragma unroll
        for (int nt = 0; nt < 2; ++nt) {
            const int ch = nt ? ch1 : ch0;
            const float* sp = S + ch * SSTR + ks * 32 + q * 8;
            const float4 v0 = *(const float4*)sp;
            const float4 v1 = *(const float4*)(sp + 4);
            Bhi[nt] = pack_hi8(v0, v1);
            Blo[nt] = pack_lo8(v0, v1, Bhi[nt]);
        }
        #pragma unroll
        for (int mi = 0; mi < 8; ++mi) {
            const size_t fo = ((size_t)((w * 8 + mi) * 16 + ks) * 64 + lane) * 8;
            const f16x8 Ahi = *(const f16x8*)(Whi + fo);
            const f16x8 Alo = *(const f16x8*)(Wlo + fo);
            acc[mi][0] = __builtin_amdgcn_mfma_f32_16x16x32_f16(Ahi, Blo[0], acc[mi][0], 0, 0, 0);
            acc[mi][0] = __builtin_amdgcn_mfma_f32_16x16x32_f16(Alo, Bhi[0], acc[mi][0], 0, 0, 0);
            acc[mi][1] = __builtin_amdgcn_mfma_f32_16x16x32_f16(Ahi, Blo[1], acc[mi][1], 0, 0, 0);
            acc[mi][1] = __builtin_amdgcn_mfma_f32_16x16x32_f16(Alo, Bhi[1], acc[mi][1], 0, 0, 0);
        }
    }
    #pragma unroll
    for (int mi = 0; mi < 8; ++mi) {
        acc[mi][0] *= (1.f / 1024.f);
        acc[mi][1] *= (1.f / 1024.f);
    }
    // ---- sweep B: main term Whi*Shi ----
    #pragma unroll 1
    for (int ks = 0; ks < 16; ++ks) {
        f16x8 Bhi[2];
        #pragma unroll
        for (int nt = 0; nt < 2; ++nt) {
            const int ch = nt ? ch1 : ch0;
            const float* sp = S + ch * SSTR + ks * 32 + q * 8;
            const float4 v0 = *(const float4*)sp;
            const float4 v1 = *(const float4*)(sp + 4);
            Bhi[nt] = pack_hi8(v0, v1);
        }
        #pragma unroll
        for (int mi = 0; mi < 8; ++mi) {
            const size_t fo = ((size_t)((w * 8 + mi) * 16 + ks) * 64 + lane) * 8;
            const f16x8 Ahi = *(const f16x8*)(Whi + fo);
            acc[mi][0] = __builtin_amdgcn_mfma_f32_16x16x32_f16(Ahi, Bhi[0], acc[mi][0], 0, 0, 0);
            acc[mi][1] = __builtin_amdgcn_mfma_f32_16x16x32_f16(Ahi, Bhi[1], acc[mi][1], 0, 0, 0);
        }
    }

    __syncthreads();   // all waves done reading S -> safe to overwrite with D
    #pragma unroll
    for (int mi = 0; mi < 8; ++mi) {
        #pragma unroll
        for (int nt = 0; nt < 2; ++nt) {
            const int ch = nt * 16 + m;
            if (ch < NCH) {
                const float4 st = {acc[mi][nt][0], acc[mi][nt][1], acc[mi][nt][2], acc[mi][nt][3]};
                *(float4*)(S + ch * SSTR + (w * 8 + mi) * 16 + q * 4) = st;
            }
        }
    }
    __syncthreads();
}

__device__ __forceinline__ void readback(float (&vals)[2][NCH],
                                         const float* __restrict__ b,
                                         const float* __restrict__ S, int tid)
{
    #pragma unroll
    for (int m = 0; m < 2; ++m) {
        const int j = 2 * tid + m;
        #pragma unroll
        for (int ch = 0; ch < NCH; ++ch) vals[m][ch] = S[ch * SSTR + j];
        vals[m][0] += b[j];
    }
}

// ---------- softplus chain + LN; writes S (ch-major) or accumulates final linear ----------
template<int P, bool FINAL>
__device__ void ln_process(float (&vals)[2][NCH],
        const float* __restrict__ g, const float* __restrict__ be,
        float* __restrict__ S, float* __restrict__ red, float* __restrict__ fin,
        float* __restrict__ sJ, float* __restrict__ sH,
        int tid, int lane, int w, float w3x, float w3y)
{
    float p[NRED];
    #pragma unroll
    for (int k = 0; k < NRED; ++k) p[k] = 0.f;

    #pragma unroll
    for (int m = 0; m < 2; ++m) {
        const float pv  = vals[m][0];
        const float e   = expf(-fabsf(pv));
        const float sig = (pv >= 0.f) ? (1.f / (1.f + e)) : (e / (1.f + e));
        const float h   = fmaxf(pv, 0.f) + log1pf(e);
        const float spp = sig * (1.f - sig);
        #pragma unroll
        for (int t = 0; t < NPR; ++t) {
            const int a = PairSet<P>::A[t], b = PairSet<P>::B[t];
            vals[m][9+t] = sig * vals[m][9+t] + spp * vals[m][1+a] * vals[m][1+b];
        }
        #pragma unroll
        for (int a = 0; a < 8; ++a) vals[m][1+a] *= sig;
        vals[m][0] = h;

        p[0] += h;
        p[1] += h * h;
        #pragma unroll
        for (int a = 0; a < 8; ++a) { p[2+a] += vals[m][1+a]; p[10+a] += h * vals[m][1+a]; }
        #pragma unroll
        for (int t = 0; t < NPR; ++t) {
            const int a = PairSet<P>::A[t], b = PairSet<P>::B[t];
            p[18+t] += vals[m][9+t];
            p[31+t] += vals[m][1+a] * vals[m][1+b];
            p[44+t] += h * vals[m][9+t];
        }
    }

    #pragma unroll
    for (int k = 0; k < NRED; ++k) p[k] = wave_sum_dpp(p[k]);
    if (lane == 63) {
        #pragma unroll
        for (int k = 0; k < NRED; ++k) red[w * NRED + k] = p[k];
    }
    __syncthreads();
    if (tid < NRED)
        fin[tid] = (red[tid] + red[NRED + tid]) + (red[2*NRED + tid] + red[3*NRED + tid]);
    __syncthreads();

    const float invH = 1.f / HDIM;
    const float mean = fin[0] * invH;
    const float var  = fin[1] * invH - mean * mean;
    const float rs   = rsqrtf(var + LN_EPS);
    float mdot[8], sdot[8];
    #pragma unroll
    for (int a = 0; a < 8; ++a) {
        mdot[a] = fin[2+a] * invH;
        sdot[a] = (fin[10+a] * invH - mean * mdot[a]) * rs;
    }
    float mdd[NPR], cy[NPR];
    #pragma unroll
    for (int t = 0; t < NPR; ++t) {
        const int a = PairSet<P>::A[t], b = PairSet<P>::B[t];
        mdd[t] = fin[18+t] * invH;
        const float mcc = fin[31+t] * invH - mdot[a] * mdot[b];
        const float mch = fin[44+t] * invH - mean * mdd[t];
        const float vdd = 2.f * (mcc + mch);
        const float sdd = (0.5f * vdd - sdot[a] * sdot[b]) * rs;
        cy[t] = 2.f * sdot[a] * sdot[b] * rs * rs - sdd * rs;
    }

    if (!FINAL) {
        #pragma unroll
        for (int m = 0; m < 2; ++m) {
            const int j = 2 * tid + m;
            const float gi = g[j], bi = be[j];
            const float y = (vals[m][0] - mean) * rs;
            S[0 * SSTR + j] = y * gi + bi;
            float cd[8];
            #pragma unroll
            for (int a = 0; a < 8; ++a) {
                cd[a] = vals[m][1+a] - mdot[a];
                S[(1+a) * SSTR + j] = (cd[a] - y * sdot[a]) * rs * gi;
            }
            #pragma unroll
            for (int t = 0; t < NPR; ++t) {
                const int a = PairSet<P>::A[t], b = PairSet<P>::B[t];
                const float cdd = vals[m][9+t] - mdd[t];
                const float ydd = cdd * rs - (cd[a]*sdot[b] + cd[b]*sdot[a]) * rs * rs
                                  + y * cy[t];
                S[(9+t) * SSTR + j] = ydd * gi;
            }
        }
    } else {
        float pf[NCH];
        #pragma unroll
        for (int k = 0; k < NCH; ++k) pf[k] = 0.f;
        #pragma unroll
        for (int m = 0; m < 2; ++m) {
            const int j = 2 * tid + m;
            const float gi = g[j], bi = be[j];
            const float w3 = m ? w3y : w3x;
            const float y = (vals[m][0] - mean) * rs;
            pf[0] += w3 * (y * gi + bi);
            float cd[8];
            #pragma unroll
            for (int a = 0; a < 8; ++a) {
                cd[a] = vals[m][1+a] - mdot[a];
                pf[1+a] += w3 * ((cd[a] - y * sdot[a]) * rs * gi);
            }
            #pragma unroll
            for (int t = 0; t < NPR; ++t) {
                const int a = PairSet<P>::A[t], b = PairSet<P>::B[t];
                const float cdd = vals[m][9+t] - mdd[t];
                const float ydd = cdd * rs - (cd[a]*sdot[b] + cd[b]*sdot[a]) * rs * rs
                                  + y * cy[t];
                pf[9+t] += w3 * (ydd * gi);
            }
        }
        #pragma unroll
        for (int k = 0; k < NCH; ++k) pf[k] = wave_sum_dpp(pf[k]);
        if (lane == 63) {
            #pragma unroll
            for (int k = 0; k < NCH; ++k) red[w * NRED + k] = pf[k];
        }
        __syncthreads();
        if (tid < NCH)
            fin[tid] = (red[tid] + red[NRED + tid]) + (red[2*NRED + tid] + red[3*NRED + tid]);
        __syncthreads();
        if (tid == 0) {
            if (P == 0) {
                #pragma unroll
                for (int a = 0; a < 8; ++a) sJ[a] = fin[1 + a];
            }
            #pragma unroll
            for (int t = 0; t < NPR; ++t) sH[P * NPR + t] = fin[9 + t];
        }
    }
}

template<int P>
__device__ void run_pass(int tid, int lane, int w, const float (&q)[8],
        const float* __restrict__ W0, const float* __restrict__ b0,
        const float* __restrict__ g0, const float* __restrict__ be0,
        const float* __restrict__ b1, const float* __restrict__ g1,
        const float* __restrict__ be1,
        const float* __restrict__ b2, const float* __restrict__ g2,
        const float* __restrict__ be2,
        const _Float16* __restrict__ Wf,
        float w3x, float w3y,
        float* S, float* red, float* fin, float* sJ, float* sH)
{
    float vals[2][NCH];

    // ---- layer 0: q(8) -> 512 (no gemm); grads = W0 row, hess = 0
    #pragma unroll
    for (int m = 0; m < 2; ++m) {
        const int i = 2 * tid + m;
        const float4 wa = *(const float4*)(W0 + i * 8);
        const float4 wb = *(const float4*)(W0 + i * 8 + 4);
        vals[m][0] = b0[i]
            + wa.x*q[0] + wa.y*q[1] + wa.z*q[2] + wa.w*q[3]
            + wb.x*q[4] + wb.y*q[5] + wb.z*q[6] + wb.w*q[7];
        vals[m][1] = wa.x; vals[m][2] = wa.y; vals[m][3] = wa.z; vals[m][4] = wa.w;
        vals[m][5] = wb.x; vals[m][6] = wb.y; vals[m][7] = wb.z; vals[m][8] = wb.w;
        #pragma unroll
        for (int t = 0; t < NPR; ++t) vals[m][9+t] = 0.f;
    }
    ln_process<P, false>(vals, g0, be0, S, red, fin, sJ, sH, tid, lane, w, w3x, w3y);
    __syncthreads();

    // ---- layer 1
    gemm_mfma(S, Wf, Wf + 262144, w, lane);
    readback(vals, b1, S, tid);
    ln_process<P, false>(vals, g1, be1, S, red, fin, sJ, sH, tid, lane, w, w3x, w3y);
    __syncthreads();

    // ---- layer 2
    gemm_mfma(S, Wf + 524288, Wf + 786432, w, lane);
    readback(vals, b2, S, tid);
    ln_process<P, true>(vals, g2, be2, S, red, fin, sJ, sH, tid, lane, w, w3x, w3y);
    __syncthreads();
}

__global__ __launch_bounds__(TPB, 3)
void lnn_kernel(const float* __restrict__ x,
    const float* __restrict__ W0, const float* __restrict__ b0,
    const float* __restrict__ g0, const float* __restrict__ be0,
    const float* __restrict__ b1, const float* __restrict__ g1,
    const float* __restrict__ be1,
    const float* __restrict__ b2, const float* __restrict__ g2,
    const float* __restrict__ be2,
    const float* __restrict__ W3,
    const _Float16* __restrict__ Wf,
    float* __restrict__ out)
{
    __shared__ __align__(16) float S[NCH * SSTR];   // 45.4 KB: state / D-staging
    __shared__ __align__(16) float red[4 * NRED];
    __shared__ __align__(16) float fin[NRED + 3];
    __shared__ float sJ[8];
    __shared__ float sH[26];

    const int tid  = threadIdx.x;
    const int lane = tid & 63;
    const int w    = tid >> 6;
    const long sample = blockIdx.x;

    float q[8];
    #pragma unroll
    for (int a = 0; a < 8; ++a) q[a] = x[sample * 8 + a];
    const float w3x = W3[2 * tid], w3y = W3[2 * tid + 1];

    run_pass<0>(tid, lane, w, q, W0, b0, g0, be0, b1, g1, be1, b2, g2, be2,
                Wf, w3x, w3y, S, red, fin, sJ, sH);
    run_pass<1>(tid, lane, w, q, W0, b0, g0, be0, b1, g1, be1, b2, g2, be2,
                Wf, w3x, w3y, S, red, fin, sJ, sH);

    if (tid == 0) {
        const int off[4] = {0, 5, 11, 18};
        double Hd[26];
        for (int t = 0; t < 26; ++t) Hd[t] = (double)sH[t];
        double r[4];
        for (int k = 0; k < 4; ++k) {
            double s = (double)sJ[k];
            for (int j = 0; j < 4; ++j) s -= Hd[off[k] + j] * (double)q[4 + j];
            r[k] = s;
        }
        double A[4][5];
        for (int jj = 0; jj < 4; ++jj) {
            for (int k = 0; k < 4; ++k) {
                const int lo = (jj < k ? jj : k) + 4;
                const int hi = (jj < k ? k : jj) + 4;
                A[jj][k] = Hd[off[hi - 4] + lo];
            }
            A[jj][4] = r[jj];
        }
        for (int c = 0; c < 4; ++c) {
            int pr = c; double mx = fabs(A[c][c]);
            for (int rr = c + 1; rr < 4; ++rr)
                if (fabs(A[rr][c]) > mx) { mx = fabs(A[rr][c]); pr = rr; }
            if (pr != c)
                for (int cc = c; cc < 5; ++cc) {
                    double t = A[c][cc]; A[c][cc] = A[pr][cc]; A[pr][cc] = t;
                }
            const double pinv = 1.0 / A[c][c];
            for (int rr = 0; rr < 4; ++rr) if (rr != c) {
                const double f = A[rr][c] * pinv;
                for (int cc = c; cc < 5; ++cc) A[rr][cc] -= f * A[c][cc];
            }
        }
        #pragma unroll
        for (int k = 0; k < 4; ++k)
            out[sample * 4 + k] = (float)(A[k][4] / A[k][k]);
    }
}

extern "C" void kernel_launch(void* const* d_in, const int* in_sizes, int n_in,
                              void* d_out, int out_size, void* d_ws, size_t ws_size,
                              hipStream_t stream) {
    const float* x   = (const float*)d_in[0];
    const float* W0  = (const float*)d_in[1];
    const float* b0  = (const float*)d_in[2];
    const float* g0  = (const float*)d_in[3];
    const float* be0 = (const float*)d_in[4];
    const float* W1  = (const float*)d_in[5];
    const float* b1  = (const float*)d_in[6];
    const float* g1  = (const float*)d_in[7];
    const float* be1 = (const float*)d_in[8];
    const float* W2  = (const float*)d_in[9];
    const float* b2  = (const float*)d_in[10];
    const float* g2  = (const float*)d_in[11];
    const float* be2 = (const float*)d_in[12];
    const float* W3  = (const float*)d_in[13];
    float* out = (float*)d_out;

    _Float16* Wf = (_Float16*)d_ws;   // 2 MB: [W1hi|W1lo|W2hi|W2lo] fragment layout
    const int B = in_sizes[0] / 8;    // 16384

    hipLaunchKernelGGL(prep_kernel, dim3(2048), dim3(256), 0, stream, W1, W2, Wf);
    hipLaunchKernelGGL(lnn_kernel, dim3(B), dim3(TPB), 0, stream,
                       x, W0, b0, g0, be0, b1, g1, be1, b2, g2, be2, W3, Wf, out);
}